// Round 4
// baseline (237.335 us; speedup 1.0000x reference)
//
#include <hip/hip_runtime.h>
#include <hip/hip_bf16.h>

// Conv2d: in (32,128,56,56) f32, w (256,128,3,3) f32, bias(256) f32
// out (32,256,56,56) f32.  Implicit-GEMM, bf16 MFMA 16x16x32.
//
// R4: R2 geometry (128x128 tile, 4 waves, 32KB LDS, 4 blocks/CU, XCD swizzle)
// + intra-budget double-buffer: stage granularity halved to c32 (A 8KB + B 8KB
// per slot), 2 slots ping-pong inside the SAME 32KB. 36 stages; per stage
// {vmcnt(0); barrier; issue 4 gl_lds into slot^1; 8 ds_read + 16 MFMA from
// slot}. One barrier/stage (36 total, same as R2) but staged loads now fly
// under a full compute phase instead of a cold drain.
//   R1 failed: dbuf via 2x LDS -> occupancy 4->2 blocks.  R3 failed: 256^2
//   8-phase -> 1 block/CU, 2 dispatch rounds, short K. This keeps both.
// Swizzle for 64B rows: store chunk cc at slot cc ^ ((row>>1)&3); read slot
// quad ^ ((l15>>1)&3). 2-way max per 16-lane group both sides (free, m136).
//
// ws:  [0, 1MB)           : w2  bf16 [9][256][128]
//      [1MB, 1MB+30.4MB)  : in_pad bf16 [32][58][64][128] (zero-padded NHWC)

typedef __bf16 bf16x8 __attribute__((ext_vector_type(8)));
typedef float f32x4 __attribute__((ext_vector_type(4)));

#define N_IMG 32
#define C_IN 128
#define HW 56
#define K_OUT 256
#define YPAD 58
#define XPAD 64
#define IN_PAD_OFF 1048576ul
#define NWGB 144                       // weight-prep blocks in fused prep

__device__ __forceinline__ void gl_lds16(const __bf16* g, __bf16* l) {
    __builtin_amdgcn_global_load_lds(
        (const __attribute__((address_space(1))) unsigned int*)(const void*)g,
        (__attribute__((address_space(3))) unsigned int*)(void*)l,
        16, 0, 0);
}

// ---- fused pre-pass: blocks [0,144) weight OIHW f32 -> [rs][ko][c] bf16;
//      blocks [144, 144+1856) input NCHW f32 -> padded NHWC bf16. (as R2)
__global__ void prep_fused(const float* __restrict__ wt, __bf16* __restrict__ w2,
                           const float* __restrict__ in, __bf16* __restrict__ in_pad) {
    __shared__ float tile[HW * 130];      // used by input path only
    if (blockIdx.x < NWGB) {
        int idx = blockIdx.x * 256 + threadIdx.x;   // 9*256*16 = 36864 items
        if (idx >= 9 * K_OUT * 16) return;
        int c8 = idx & 15;
        int ko = (idx >> 4) & 255;
        int rs = idx >> 12;
        const float* src = wt + ((size_t)ko * C_IN + c8 * 8) * 9 + rs;
        bf16x8 v8;
#pragma unroll
        for (int k = 0; k < 8; ++k) v8[k] = (__bf16)src[k * 9];
        *(bf16x8*)(w2 + (size_t)idx * 8) = v8;      // = [rs][ko][c8*8..+8]
        return;
    }
    int bid = blockIdx.x - NWGB;          // 32*58 = 1856
    int y = bid % YPAD;
    int n = bid / YPAD;
    int h = y - 1;
    bool interior = (h >= 0 && h < HW);
    int t = threadIdx.x;
    if (interior) {
        const float* src = in + (size_t)n * C_IN * (HW * HW) + (size_t)h * HW;
#pragma unroll 1
        for (int idx = t; idx < C_IN * 14; idx += 256) {   // float4 reads
            int c = idx / 14, g = idx % 14;
            f32x4 v = *(const f32x4*)(src + (size_t)c * (HW * HW) + g * 4);
            int w = g * 4;
            tile[(w + 0) * 130 + c] = v.x;
            tile[(w + 1) * 130 + c] = v.y;
            tile[(w + 2) * 130 + c] = v.z;
            tile[(w + 3) * 130 + c] = v.w;
        }
    }
    __syncthreads();
    __bf16* dst = in_pad + (size_t)(n * YPAD + y) * XPAD * C_IN;
#pragma unroll 1
    for (int idx = t; idx < XPAD * 16; idx += 256) {       // 16B stores
        int x = idx >> 4, cg = idx & 15;
        bf16x8 v8;
        if (interior && x >= 1 && x <= HW) {
            const float* tp = tile + (x - 1) * 130 + cg * 8;
#pragma unroll
            for (int k = 0; k < 8; ++k) v8[k] = (__bf16)tp[k];
        } else {
#pragma unroll
            for (int k = 0; k < 8; ++k) v8[k] = (__bf16)0.f;
        }
        *(bf16x8*)(dst + x * C_IN + cg * 8) = v8;
    }
}

// ---------------- main kernel: c32 ping-pong pipelined implicit-GEMM conv ------
__global__ __launch_bounds__(256, 4) void conv_mfma(
        const __bf16* __restrict__ in_pad,   // [32][58][64][128]
        const __bf16* __restrict__ w2,       // [9][256][128]
        const float* __restrict__ bias,
        float* __restrict__ out)             // [32][256][56][56]
{
    __shared__ __bf16 sA[2][4096];           // 2 x 8 KB: 128 rows x 32 elem
    __shared__ __bf16 sB[2][4096];           // 2 x 8 KB: 128 ko  x 32 elem

    // T1: XCD-chunked bijective remap (1792 = 8 XCDs x 224 blocks).
    int bid  = (blockIdx.x & 7) * 224 + (blockIdx.x >> 3);
    int kot  = bid & 1;
    int wt_  = (bid >> 1) & 3;
    int rest = bid >> 3;
    int ht   = rest % 7;
    int n    = rest / 7;

    int h0  = ht * 8;
    int w0  = (wt_ == 3) ? 40 : wt_ * 16;    // last w-tile overlaps: no masks
    int ko0 = kot * 128;

    int tid  = threadIdx.x;
    int lane = tid & 63;
    int wave = tid >> 6;
    int mw   = wave & 1;
    int nw   = wave >> 1;
    int l15  = lane & 15;
    int quad = lane >> 4;

    // staging source offsets (swizzle baked into per-lane global source)
    int aoff[2], boff[2];
#pragma unroll
    for (int j = 0; j < 2; ++j) {
        int id  = j * 256 + tid;             // chunk id within 8KB unit (0..511)
        int riu = id >> 2, cs = id & 3;
        int i = riu >> 4, x = riu & 15;      // A row = i*16 + x
        aoff[j] = (i * XPAD + x) * C_IN + (cs ^ ((x >> 1) & 3)) * 8;
        int ko = riu;                        // B row = ko
        boff[j] = ko * C_IN + (cs ^ ((ko >> 1) & 3)) * 8;
    }

    // fragment ds_read offsets (element units within a slot)
    int sl   = quad ^ ((l15 >> 1) & 3);      // swizzled slot chunk
    int aRd  = (mw * 64 + l15) * 32 + sl * 8;    // + mf*512
    int bRd  = (nw * 64 + l15) * 32 + sl * 8;    // + nf*512

    const __bf16* aG = in_pad + (((size_t)n * YPAD + h0) * XPAD + w0) * C_IN;
    const __bf16* bG = w2 + (size_t)ko0 * C_IN;

    f32x4 acc[4][4] = {};

    // stage u (0..35): rs = u>>2, c0 = (u&3)*32
    auto STAGE = [&](int u, int p) {
        int rs = u >> 2;
        int c0 = (u & 3) << 5;
        int r  = (rs * 11) >> 5;             // rs/3 for rs in 0..8
        int s  = rs - 3 * r;
        const __bf16* aS = aG + (r * XPAD + s) * C_IN + c0;
        const __bf16* bS = bG + (size_t)rs * (K_OUT * C_IN) + c0;
        gl_lds16(aS + aoff[0], &sA[p][0] + wave * 512);
        gl_lds16(aS + aoff[1], &sA[p][0] + 2048 + wave * 512);
        gl_lds16(bS + boff[0], &sB[p][0] + wave * 512);
        gl_lds16(bS + boff[1], &sB[p][0] + 2048 + wave * 512);
    };

    STAGE(0, 0);                             // prologue: stage 0 in flight

#pragma unroll 2
    for (int u = 0; u < 36; ++u) {
        int p = u & 1;
        // own loads into slot p (issued last iter) arrived; barrier publishes.
        asm volatile("s_waitcnt vmcnt(0)" ::: "memory");
        __builtin_amdgcn_s_barrier();
        asm volatile("" ::: "memory");
        // next stage flies under this stage's ds_read + MFMA.
        if (u < 35) STAGE(u + 1, p ^ 1);

        bf16x8 a[4], b[4];
#pragma unroll
        for (int mf = 0; mf < 4; ++mf)
            a[mf] = *(const bf16x8*)(&sA[p][0] + mf * 512 + aRd);
#pragma unroll
        for (int nf = 0; nf < 4; ++nf)
            b[nf] = *(const bf16x8*)(&sB[p][0] + nf * 512 + bRd);
        asm volatile("s_waitcnt lgkmcnt(0)" ::: "memory");
        __builtin_amdgcn_sched_barrier(0);
#pragma unroll
        for (int mf = 0; mf < 4; ++mf)
#pragma unroll
            for (int nf = 0; nf < 4; ++nf)
                acc[mf][nf] = __builtin_amdgcn_mfma_f32_16x16x32_bf16(
                    a[mf], b[nf], acc[mf][nf], 0, 0, 0);
    }

    // epilogue: D[row=quad*4+reg][col=l15]; row -> w, col -> ko-within-16
#pragma unroll
    for (int nf = 0; nf < 4; ++nf) {
        int ko = ko0 + nw * 64 + nf * 16 + l15;
        float bs = bias[ko];
        float* outb = out + (size_t)(n * K_OUT + ko) * (HW * HW)
                          + (size_t)(h0 + mw * 4) * HW + w0 + quad * 4;
#pragma unroll
        for (int mf = 0; mf < 4; ++mf) {
            f32x4 v = acc[mf][nf];
            v = v + bs;
            *(f32x4*)(outb + mf * HW) = v;
        }
    }
}

// ---------------- fallback: naive direct conv (only if ws too small) -----------
__global__ void conv_naive(const float* __restrict__ in, const float* __restrict__ wt,
                           const float* __restrict__ bias, float* __restrict__ out) {
    size_t idx = (size_t)blockIdx.x * 256 + threadIdx.x;
    size_t total = (size_t)N_IMG * K_OUT * HW * HW;
    if (idx >= total) return;
    int w  = idx % HW;
    int h  = (idx / HW) % HW;
    int ko = (idx / (HW * HW)) % K_OUT;
    int n  = idx / ((size_t)HW * HW * K_OUT);
    float acc = bias[ko];
    for (int c = 0; c < C_IN; ++c)
        for (int r = 0; r < 3; ++r) {
            int y = h + r - 1;
            if (y < 0 || y >= HW) continue;
            for (int s = 0; s < 3; ++s) {
                int x = w + s - 1;
                if (x < 0 || x >= HW) continue;
                acc += in[((size_t)(n * C_IN + c) * HW + y) * HW + x]
                     * wt[((size_t)ko * C_IN + c) * 9 + r * 3 + s];
            }
        }
    out[idx] = acc;
}

extern "C" void kernel_launch(void* const* d_in, const int* in_sizes, int n_in,
                              void* d_out, int out_size, void* d_ws, size_t ws_size,
                              hipStream_t stream) {
    const float* in   = (const float*)d_in[0];
    const float* wt   = (const float*)d_in[1];
    const float* bias = (const float*)d_in[2];
    float* out = (float*)d_out;

    size_t need = IN_PAD_OFF + (size_t)N_IMG * YPAD * XPAD * C_IN * 2;
    if (ws_size >= need) {
        __bf16* w2     = (__bf16*)d_ws;
        __bf16* in_pad = (__bf16*)((char*)d_ws + IN_PAD_OFF);
        prep_fused<<<NWGB + N_IMG * YPAD, 256, 0, stream>>>(wt, w2, in, in_pad);
        conv_mfma<<<N_IMG * 7 * 4 * 2, 256, 0, stream>>>(in_pad, w2, bias, out);
    } else {
        size_t total = (size_t)N_IMG * K_OUT * HW * HW;
        conv_naive<<<(unsigned)((total + 255) / 256), 256, 0, stream>>>(in, wt, bias, out);
    }
}